// Round 1
// baseline (6357.335 us; speedup 1.0000x reference)
//
#include <hip/hip_runtime.h>
#include <math.h>

// Sparse2L: 10-step ISTA sparse coding.
//  per step: R = x@W - inputs; causes = (1+exp(-(u@V)))*0.5;
//            x = softthr(x - 2*lr*(R@W^T), lr*gamma*upsample(causes));
//            gin = (0.5-causes) * maxpool2x2(x) * gamma;   (dcauses == 0.5-causes)
//            u = softthr(u - lr*(gin@V^T), lr*gamma/10)
//  output = x9 @ W   (outputs of scan iteration 10, computed from x after 9 updates)

#define NB 4096
#define IN_DIM 512
#define OUT_DIM 4096
#define CAUSES_DIM 256
#define POOLED_DIM 1024

static constexpr float LR = 0.001f;
static constexpr float GAMMA = 0.1f;

enum { EP_R = 0, EP_OUT, EP_CAUSES, EP_XUP, EP_UUP };

__device__ __forceinline__ float softthr(float v, float t) {
    return fmaxf(v - t, 0.0f) + fminf(v + t, 0.0f);
}

// ---------------------------------------------------------------------------
// Generic fp32 GEMM: C = A(MxK, row-major) * B, with B either [K,N] (BT=false)
// or [N,K] (BT=true, i.e. C = A*B^T). Fused epilogues per EP.
//   EP_R:      out = acc - aux          (aux = inputs, N == IN_DIM)
//   EP_OUT:    out = acc
//   EP_CAUSES: out = (1+exp(-acc))*0.5
//   EP_XUP:    x-update: out(=x) = softthr(x - 2*LR*acc, LR*GAMMA*causes_up)
//              aux = causes [NB, POOLED_DIM]
//   EP_UUP:    u-update: out(=u) = softthr(u - LR*acc, LR*GAMMA/10)
// ---------------------------------------------------------------------------
template<int BM, int BN, int BK, int TM, int TN, bool BT, int EP>
__global__ __launch_bounds__(256, 2)
void gemm_f32(const float* __restrict__ A, const float* __restrict__ Bm,
              const float* __restrict__ aux, float* __restrict__ out,
              int M, int N, int K)
{
    static_assert(BK == 16, "loaders assume BK==16");
    static_assert((BM / TM) * (BN / TN) == 256, "256 threads");
    __shared__ float As[BK][BM + 4];
    __shared__ float Bs[BK][BN + 4];

    const int t  = threadIdx.x;
    const int m0 = blockIdx.y * BM;
    const int n0 = blockIdx.x * BN;
    constexpr int NTH = BN / TN;
    const int tx = t % NTH;
    const int ty = t / NTH;

    float acc[TM][TN];
#pragma unroll
    for (int i = 0; i < TM; i++)
#pragma unroll
        for (int j = 0; j < TN; j++) acc[i][j] = 0.0f;

    // transpose-load indices (A always; B when BT): 4 threads cover BK=16 floats
    const int lk4  = (t & 3) * 4;  // k offset
    const int lrow = t >> 2;       // 0..63 (m or n)
    constexpr int L_ROWS = 64;     // rows covered per pass

    for (int k0 = 0; k0 < K; k0 += BK) {
        // ---- load A tile (row-major [M,K]) into As[k][m] ----
#pragma unroll
        for (int p = 0; p < BM / L_ROWS; p++) {
            const int m = lrow + p * L_ROWS;
            float4 v = *(const float4*)&A[(size_t)(m0 + m) * K + k0 + lk4];
            As[lk4 + 0][m] = v.x; As[lk4 + 1][m] = v.y;
            As[lk4 + 2][m] = v.z; As[lk4 + 3][m] = v.w;
        }
        // ---- load B tile ----
        if (BT) {  // B is [N,K] row-major -> Bs[k][n]
#pragma unroll
            for (int p = 0; p < BN / L_ROWS; p++) {
                const int n = lrow + p * L_ROWS;
                float4 v = *(const float4*)&Bm[(size_t)(n0 + n) * K + k0 + lk4];
                Bs[lk4 + 0][n] = v.x; Bs[lk4 + 1][n] = v.y;
                Bs[lk4 + 2][n] = v.z; Bs[lk4 + 3][n] = v.w;
            }
        } else {   // B is [K,N] row-major -> Bs[k][n], coalesced along n
            constexpr int TPR  = BN / 4;       // threads per k-row
            constexpr int ROWS = 256 / TPR;    // k-rows per pass
            const int bn4 = (t % TPR) * 4;
            const int bk  = t / TPR;
#pragma unroll
            for (int p = 0; p < BK / ROWS; p++) {
                float4 v = *(const float4*)&Bm[(size_t)(k0 + bk + p * ROWS) * N + n0 + bn4];
                *(float4*)&Bs[bk + p * ROWS][bn4] = v;
            }
        }
        __syncthreads();

#pragma unroll
        for (int k = 0; k < BK; k++) {
            float a[TM], b[TN];
#pragma unroll
            for (int i = 0; i < TM; i += 4)
                *(float4*)&a[i] = *(const float4*)&As[k][ty * TM + i];
#pragma unroll
            for (int j = 0; j < TN; j += 4)
                *(float4*)&b[j] = *(const float4*)&Bs[k][tx * TN + j];
#pragma unroll
            for (int i = 0; i < TM; i++)
#pragma unroll
                for (int j = 0; j < TN; j++)
                    acc[i][j] = fmaf(a[i], b[j], acc[i][j]);
        }
        __syncthreads();
    }

    // ---- epilogue ----
    const int r0 = m0 + ty * TM;
    const int c0 = n0 + tx * TN;
#pragma unroll
    for (int i = 0; i < TM; i++) {
        const int r = r0 + i;
#pragma unroll
        for (int j = 0; j < TN; j++) {
            const int c = c0 + j;
            const float v = acc[i][j];
            if (EP == EP_R) {
                out[(size_t)r * N + c] = v - aux[(size_t)r * N + c];
            } else if (EP == EP_OUT) {
                out[(size_t)r * N + c] = v;
            } else if (EP == EP_CAUSES) {
                out[(size_t)r * N + c] = (1.0f + expf(-v)) * 0.5f;
            } else if (EP == EP_XUP) {
                // c indexes the 64x64 code map; causes_up gathers pooled map
                const int mr = c >> 6, mc = c & 63;
                const int pidx = ((mr >> 1) << 5) | (mc >> 1);
                const float cz = aux[(size_t)r * POOLED_DIM + pidx];
                const float th = LR * GAMMA * cz;
                const size_t idx = (size_t)r * OUT_DIM + c;
                const float xv = out[idx] - (2.0f * LR) * v;
                out[idx] = softthr(xv, th);
            } else { // EP_UUP
                const size_t idx = (size_t)r * CAUSES_DIM + c;
                const float uv = out[idx] - LR * v;
                out[idx] = softthr(uv, LR * GAMMA * 0.1f);
            }
        }
    }
}

// ---------------------------------------------------------------------------
// maxpool 2x2 over the 64x64 code map + gin = (0.5 - causes) * pool * GAMMA
// one block per batch row; row staged in LDS (16 KB)
// ---------------------------------------------------------------------------
__global__ __launch_bounds__(256)
void poolgin_kernel(const float* __restrict__ x, const float* __restrict__ causes,
                    float* __restrict__ gin)
{
    __shared__ float row[OUT_DIM];
    const int b = blockIdx.x;
    const float4* xr = (const float4*)(x + (size_t)b * OUT_DIM);
#pragma unroll
    for (int p = 0; p < 4; p++) {
        const int i4 = threadIdx.x + p * 256;
        *(float4*)&row[i4 * 4] = xr[i4];
    }
    __syncthreads();
#pragma unroll
    for (int p = 0; p < 4; p++) {
        const int idx = threadIdx.x + p * 256;     // pooled index 0..1023
        const int mr = idx >> 5, mc = idx & 31;
        const int base = mr * 128 + mc * 2;        // (2*mr)*64 + 2*mc
        const float m = fmaxf(fmaxf(row[base], row[base + 1]),
                              fmaxf(row[base + 64], row[base + 65]));
        gin[(size_t)b * POOLED_DIM + idx] =
            (0.5f - causes[(size_t)b * POOLED_DIM + idx]) * m * GAMMA;
    }
}

__global__ void fill_f32(float* __restrict__ p, float v, size_t n4) {
    const float4 f = {v, v, v, v};
    for (size_t i = (size_t)blockIdx.x * 256 + threadIdx.x; i < n4;
         i += (size_t)gridDim.x * 256)
        ((float4*)p)[i] = f;
}

__global__ void neg_copy(const float* __restrict__ in, float* __restrict__ out, size_t n4) {
    for (size_t i = (size_t)blockIdx.x * 256 + threadIdx.x; i < n4;
         i += (size_t)gridDim.x * 256) {
        float4 v = ((const float4*)in)[i];
        ((float4*)out)[i] = {-v.x, -v.y, -v.z, -v.w};
    }
}

extern "C" void kernel_launch(void* const* d_in, const int* in_sizes, int n_in,
                              void* d_out, int out_size, void* d_ws, size_t ws_size,
                              hipStream_t stream)
{
    const float* inputs = (const float*)d_in[0];   // [4096, 512]
    const float* W      = (const float*)d_in[1];   // [4096, 512]  (OUT_DIM x IN_DIM)
    const float* V      = (const float*)d_in[2];   // [256, 1024]
    float* out = (float*)d_out;                    // [4096, 512]

    // workspace layout (~108 MB)
    float* x      = (float*)d_ws;                          // [4096, 4096]
    float* R      = x      + (size_t)NB * OUT_DIM;         // [4096, 512]
    float* causes = R      + (size_t)NB * IN_DIM;          // [4096, 1024]
    float* gin    = causes + (size_t)NB * POOLED_DIM;      // [4096, 1024]
    float* u      = gin    + (size_t)NB * POOLED_DIM;      // [4096, 256]

    // init (ws is poisoned before every timed launch)
    fill_f32<<<2048, 256, 0, stream>>>(x, 0.0f, (size_t)NB * OUT_DIM / 4);
    fill_f32<<<512, 256, 0, stream>>>(u, 0.1f, (size_t)NB * CAUSES_DIM / 4);
    neg_copy<<<512, 256, 0, stream>>>(inputs, R, (size_t)NB * IN_DIM / 4);  // R0 = 0@W - inputs

    for (int t = 0; t < 9; t++) {
        if (t > 0) {
            // R = x@W - inputs   [4096,512] = [4096,4096]@[4096,512]
            gemm_f32<128, 64, 16, 8, 4, false, EP_R>
                <<<dim3(IN_DIM / 64, NB / 128), 256, 0, stream>>>(
                    x, W, inputs, R, NB, IN_DIM, OUT_DIM);
        }
        // causes = (1+exp(-(u@V)))*0.5   [4096,1024]
        gemm_f32<128, 64, 16, 8, 4, false, EP_CAUSES>
            <<<dim3(POOLED_DIM / 64, NB / 128), 256, 0, stream>>>(
                u, V, nullptr, causes, NB, POOLED_DIM, CAUSES_DIM);
        // x = softthr(x - 2*LR*(R@W^T), LR*GAMMA*causes_up)   [4096,4096]
        gemm_f32<128, 128, 16, 8, 8, true, EP_XUP>
            <<<dim3(OUT_DIM / 128, NB / 128), 256, 0, stream>>>(
                R, W, causes, x, NB, OUT_DIM, IN_DIM);
        if (t < 8) {  // u9 is never consumed -> skip pool+u-update on last step
            poolgin_kernel<<<NB, 256, 0, stream>>>(x, causes, gin);
            // u = softthr(u - LR*(gin@V^T), LR*GAMMA/10)   [4096,256]
            gemm_f32<128, 64, 16, 8, 4, true, EP_UUP>
                <<<dim3(CAUSES_DIM / 64, NB / 128), 256, 0, stream>>>(
                    gin, V, nullptr, u, NB, CAUSES_DIM, POOLED_DIM);
        }
    }
    // rec = x9 @ W
    gemm_f32<128, 64, 16, 8, 4, false, EP_OUT>
        <<<dim3(IN_DIM / 64, NB / 128), 256, 0, stream>>>(
            x, W, nullptr, out, NB, IN_DIM, OUT_DIM);
}

// Round 2
// 1394.945 us; speedup vs baseline: 4.5574x; 4.5574x over previous
//
#include <hip/hip_runtime.h>
#include <math.h>

// Sparse2L, bf16-MFMA version.
//  per step: R = x@W - inputs; causes = (1+exp(-(u@V)))*0.5;
//            x = softthr(x - 2*lr*(R@W^T), lr*gamma*upsample(causes));
//            gin = (0.5-causes) * maxpool2x2(x) * gamma;
//            u = softthr(u - lr*(gin@V^T), lr*gamma/10)
//  output = x9 @ W
// All GEMMs: A [M][K] bf16 row-major, B stored as B^T-layout [N][K] bf16.
// MFMA 16x16x32 bf16; frag A/B: row=lane&15, k=(lane>>4)*8+i (contiguous 8);
// D: col=lane&15, row=(lane>>4)*4+reg (m89-verified).
// LDS tiles [rows][64] bf16 (128B rows) with seg^(row&7) XOR swizzle applied
// at BOTH the pre-swizzled global_load_lds source and the ds_read_b128 reads.

#define NB 4096
#define IN_DIM 512
#define OUT_DIM 4096
#define CAUSES_DIM 256
#define POOLED_DIM 1024

typedef __attribute__((ext_vector_type(8))) short short8;
typedef __attribute__((ext_vector_type(4))) float f32x4;

static constexpr float LR = 0.001f;
static constexpr float GAMMA = 0.1f;

enum { EP_R = 0, EP_OUT, EP_CAUSES, EP_XUP, EP_UUP };

__device__ __forceinline__ float softthr(float v, float t) {
    return fmaxf(v - t, 0.0f) + fminf(v + t, 0.0f);
}
__device__ __forceinline__ unsigned short f2bf(float f) {
    unsigned int u = __builtin_bit_cast(unsigned int, f);
    u = (u + 0x7fffu + ((u >> 16) & 1u)) >> 16;
    return (unsigned short)u;
}
__device__ __forceinline__ void gload_lds16(const unsigned short* g, unsigned short* l) {
    __builtin_amdgcn_global_load_lds(
        (const __attribute__((address_space(1))) void*)g,
        (__attribute__((address_space(3))) void*)l, 16, 0, 0);
}

// ---------------------------------------------------------------------------
// bf16 MFMA GEMM, 256 threads = 4 waves (2x2), BK=64, per-wave BM/2 x BN/2.
// out0/out1 meaning per EP (see launch).
// ---------------------------------------------------------------------------
template<int BM, int BN, int EP>
__global__ __launch_bounds__(256)
void gemm_bf16(const unsigned short* __restrict__ A, const unsigned short* __restrict__ B,
               const float* __restrict__ aux, void* __restrict__ out0,
               void* __restrict__ out1, int M, int N, int K)
{
    constexpr int WM = BM / 2, WN = BN / 2;
    constexpr int FM = WM / 16, FN = WN / 16;
    static_assert(FM >= 1 && FN >= 1, "");
    __shared__ unsigned short As[BM * 64];
    __shared__ unsigned short Bs[BN * 64];

    const int t    = threadIdx.x;
    const int lane = t & 63, wid = t >> 6;
    const int l15  = lane & 15, l7 = lane & 7, g = lane >> 4;
    const int m0 = blockIdx.y * BM, n0 = blockIdx.x * BN;
    const int wm0 = (wid >> 1) * WM, wn0 = (wid & 1) * WN;

    f32x4 acc[FM][FN];
#pragma unroll
    for (int fi = 0; fi < FM; fi++)
#pragma unroll
        for (int fj = 0; fj < FN; fj++) acc[fi][fj] = (f32x4){0.f, 0.f, 0.f, 0.f};

    for (int k0 = 0; k0 < K; k0 += 64) {
        // ---- stage A tile: rows [m0, m0+BM), 64 k, swizzled segs ----
#pragma unroll
        for (int j = 0; j < BM / 32; j++) {
            const int idx = j * 256 + t;
            const int row = idx >> 3;
            const int sl  = (idx & 7) ^ (row & 7);
            gload_lds16(A + (size_t)(m0 + row) * K + k0 + sl * 8,
                        As + (size_t)(idx & ~63) * 8);
        }
        // ---- stage B tile (B^T-layout input): rows [n0, n0+BN) ----
#pragma unroll
        for (int j = 0; j < BN / 32; j++) {
            const int idx = j * 256 + t;
            const int row = idx >> 3;
            const int sl  = (idx & 7) ^ (row & 7);
            gload_lds16(B + (size_t)(n0 + row) * K + k0 + sl * 8,
                        Bs + (size_t)(idx & ~63) * 8);
        }
        __syncthreads();   // compiler drains vmcnt before s_barrier

#pragma unroll
        for (int ks = 0; ks < 2; ks++) {
            const int so = (((ks * 4) + g) ^ l7) * 8;  // swizzled k-seg (shorts)
            short8 af[FM], bfv[FN];
#pragma unroll
            for (int fi = 0; fi < FM; fi++)
                af[fi] = *(const short8*)&As[(wm0 + fi * 16 + l15) * 64 + so];
#pragma unroll
            for (int fj = 0; fj < FN; fj++)
                bfv[fj] = *(const short8*)&Bs[(wn0 + fj * 16 + l15) * 64 + so];
#pragma unroll
            for (int fi = 0; fi < FM; fi++)
#pragma unroll
                for (int fj = 0; fj < FN; fj++)
                    acc[fi][fj] = __builtin_amdgcn_mfma_f32_16x16x32_bf16(
                        af[fi], bfv[fj], acc[fi][fj], 0, 0, 0);
        }
        __syncthreads();
    }

    // ---- epilogue ----
#pragma unroll
    for (int fi = 0; fi < FM; fi++) {
#pragma unroll
        for (int fj = 0; fj < FN; fj++) {
#pragma unroll
            for (int r = 0; r < 4; r++) {
                const int row = m0 + wm0 + fi * 16 + g * 4 + r;
                const int col = n0 + wn0 + fj * 16 + l15;
                const float v = acc[fi][fj][r];
                if (EP == EP_R) {
                    ((unsigned short*)out0)[(size_t)row * N + col] =
                        f2bf(v - aux[(size_t)row * N + col]);
                } else if (EP == EP_OUT) {
                    ((float*)out0)[(size_t)row * N + col] = v;
                } else if (EP == EP_CAUSES) {
                    ((float*)out0)[(size_t)row * N + col] = (1.0f + expf(-v)) * 0.5f;
                } else if (EP == EP_XUP) {
                    const int mr = col >> 6, mc = col & 63;
                    const int pidx = ((mr >> 1) << 5) | (mc >> 1);
                    const float cz = aux[(size_t)row * POOLED_DIM + pidx];
                    float* xp = (float*)out0;
                    const size_t idx = (size_t)row * OUT_DIM + col;
                    const float xv = softthr(xp[idx] - 2.0f * LR * v, LR * GAMMA * cz);
                    xp[idx] = xv;
                    ((unsigned short*)out1)[idx] = f2bf(xv);
                } else { // EP_UUP
                    float* up = (float*)out0;
                    const size_t idx = (size_t)row * CAUSES_DIM + col;
                    const float uv = softthr(up[idx] - LR * v, LR * GAMMA * 0.1f);
                    up[idx] = uv;
                    ((unsigned short*)out1)[idx] = f2bf(uv);
                }
            }
        }
    }
}

// ---------------------------------------------------------------------------
// maxpool2x2 + gin = (0.5-causes)*pool*GAMMA, bf16 out. One block per row.
// ---------------------------------------------------------------------------
__global__ __launch_bounds__(256)
void poolgin_kernel(const float* __restrict__ x, const float* __restrict__ causes,
                    unsigned short* __restrict__ ginbf)
{
    __shared__ float row[OUT_DIM];
    const int b = blockIdx.x;
    const float4* xr = (const float4*)(x + (size_t)b * OUT_DIM);
#pragma unroll
    for (int p = 0; p < 4; p++) {
        const int i4 = threadIdx.x + p * 256;
        *(float4*)&row[i4 * 4] = xr[i4];
    }
    __syncthreads();
#pragma unroll
    for (int p = 0; p < 4; p++) {
        const int idx = threadIdx.x + p * 256;     // pooled index 0..1023
        const int mr = idx >> 5, mc = idx & 31;
        const int base = mr * 128 + mc * 2;
        const float m = fmaxf(fmaxf(row[base], row[base + 1]),
                              fmaxf(row[base + 64], row[base + 65]));
        ginbf[(size_t)b * POOLED_DIM + idx] =
            f2bf((0.5f - causes[(size_t)b * POOLED_DIM + idx]) * m * GAMMA);
    }
}

// ---------------------------------------------------------------------------
// setup kernels
// ---------------------------------------------------------------------------
__global__ void cast_bf16_k(const float* __restrict__ in, unsigned short* __restrict__ out,
                            int n4, int neg)
{
    const int i = blockIdx.x * 256 + threadIdx.x;
    if (i >= n4) return;
    float4 v = ((const float4*)in)[i];
    if (neg) { v.x = -v.x; v.y = -v.y; v.z = -v.z; v.w = -v.w; }
    union { unsigned short s[4]; unsigned long long u; } p;
    p.s[0] = f2bf(v.x); p.s[1] = f2bf(v.y); p.s[2] = f2bf(v.z); p.s[3] = f2bf(v.w);
    ((unsigned long long*)out)[i] = p.u;
}

// transpose+cast: f32 in[R][C] -> bf16 out[C][R]
__global__ __launch_bounds__(256)
void transpose_cast_k(const float* __restrict__ in, unsigned short* __restrict__ out,
                      int R, int C)
{
    __shared__ float tile[32][33];
    const int bx = blockIdx.x * 32, by = blockIdx.y * 32;
    const int tx = threadIdx.x % 32, ty = threadIdx.x / 32;
#pragma unroll
    for (int i = 0; i < 32; i += 8)
        tile[ty + i][tx] = in[(size_t)(by + ty + i) * C + bx + tx];
    __syncthreads();
#pragma unroll
    for (int i = 0; i < 32; i += 8)
        out[(size_t)(bx + ty + i) * R + by + tx] = f2bf(tile[tx][ty + i]);
}

__global__ void fill_zero_f32(float* __restrict__ p, size_t n4) {
    for (size_t i = (size_t)blockIdx.x * 256 + threadIdx.x; i < n4;
         i += (size_t)gridDim.x * 256)
        ((float4*)p)[i] = (float4){0.f, 0.f, 0.f, 0.f};
}

__global__ void fill_u_k(float* __restrict__ u, unsigned short* __restrict__ ubf, int n) {
    const int i = blockIdx.x * 256 + threadIdx.x;
    if (i >= n) return;
    u[i] = 0.1f;
    ubf[i] = f2bf(0.1f);
}

extern "C" void kernel_launch(void* const* d_in, const int* in_sizes, int n_in,
                              void* d_out, int out_size, void* d_ws, size_t ws_size,
                              hipStream_t stream)
{
    const float* inputs = (const float*)d_in[0];   // [4096, 512]
    const float* W      = (const float*)d_in[1];   // [4096, 512]
    const float* V      = (const float*)d_in[2];   // [256, 1024]
    float* out = (float*)d_out;                    // [4096, 512]

    // workspace layout (~139 MB)
    char* w = (char*)d_ws;
    float* x      = (float*)w;  w += (size_t)NB * OUT_DIM * 4;           // 64 MB
    float* causes = (float*)w;  w += (size_t)NB * POOLED_DIM * 4;        // 16 MB
    float* u      = (float*)w;  w += (size_t)NB * CAUSES_DIM * 4;        //  4 MB
    unsigned short* xbf  = (unsigned short*)w; w += (size_t)NB * OUT_DIM * 2;      // 32 MB
    unsigned short* Rbf  = (unsigned short*)w; w += (size_t)NB * IN_DIM * 2;       //  4 MB
    unsigned short* gbf  = (unsigned short*)w; w += (size_t)NB * POOLED_DIM * 2;   //  8 MB
    unsigned short* ubf  = (unsigned short*)w; w += (size_t)NB * CAUSES_DIM * 2;   //  2 MB
    unsigned short* Wbf  = (unsigned short*)w; w += (size_t)OUT_DIM * IN_DIM * 2;  //  4 MB
    unsigned short* WTbf = (unsigned short*)w; w += (size_t)OUT_DIM * IN_DIM * 2;  //  4 MB
    unsigned short* Vbf  = (unsigned short*)w; w += (size_t)CAUSES_DIM * POOLED_DIM * 2;
    unsigned short* VTbf = (unsigned short*)w;

    // ---- setup: bf16 casts / transposes / state init ----
    cast_bf16_k<<<OUT_DIM * IN_DIM / 4 / 256, 256, 0, stream>>>(W, Wbf, OUT_DIM * IN_DIM / 4, 0);
    cast_bf16_k<<<CAUSES_DIM * POOLED_DIM / 4 / 256, 256, 0, stream>>>(V, Vbf, CAUSES_DIM * POOLED_DIM / 4, 0);
    transpose_cast_k<<<dim3(IN_DIM / 32, OUT_DIM / 32), 256, 0, stream>>>(W, WTbf, OUT_DIM, IN_DIM);
    transpose_cast_k<<<dim3(POOLED_DIM / 32, CAUSES_DIM / 32), 256, 0, stream>>>(V, VTbf, CAUSES_DIM, POOLED_DIM);
    fill_zero_f32<<<2048, 256, 0, stream>>>(x, (size_t)NB * OUT_DIM / 4);
    fill_u_k<<<NB * CAUSES_DIM / 256, 256, 0, stream>>>(u, ubf, NB * CAUSES_DIM);
    cast_bf16_k<<<NB * IN_DIM / 4 / 256, 256, 0, stream>>>(inputs, Rbf, NB * IN_DIM / 4, 1); // R0 = -inputs

    for (int t = 0; t < 9; t++) {
        if (t > 0) {
            // Rbf = bf16(x@W - inputs)  : A=xbf [4096][4096], B^T=WTbf [512][4096]
            gemm_bf16<64, 64, EP_R><<<dim3(IN_DIM / 64, NB / 64), 256, 0, stream>>>(
                xbf, WTbf, inputs, Rbf, nullptr, NB, IN_DIM, OUT_DIM);
        }
        // causes = (1+exp(-(u@V)))*0.5 : A=ubf [4096][256], B^T=VTbf [1024][256]
        gemm_bf16<64, 64, EP_CAUSES><<<dim3(POOLED_DIM / 64, NB / 64), 256, 0, stream>>>(
            ubf, VTbf, nullptr, causes, nullptr, NB, POOLED_DIM, CAUSES_DIM);
        // x = softthr(x - 2lr*(R@W^T), lr*g*up(causes)) : A=Rbf, B^T=Wbf [4096][512]
        gemm_bf16<128, 128, EP_XUP><<<dim3(OUT_DIM / 128, NB / 128), 256, 0, stream>>>(
            Rbf, Wbf, causes, x, xbf, NB, OUT_DIM, IN_DIM);
        if (t < 8) {
            poolgin_kernel<<<NB, 256, 0, stream>>>(x, causes, gbf);
            // u = softthr(u - lr*(gin@V^T), lr*g/10) : A=gbf, B^T=Vbf [256][1024]
            gemm_bf16<64, 64, EP_UUP><<<dim3(CAUSES_DIM / 64, NB / 64), 256, 0, stream>>>(
                gbf, Vbf, nullptr, u, ubf, NB, CAUSES_DIM, POOLED_DIM);
        }
    }
    // rec = x9 @ W
    gemm_bf16<64, 64, EP_OUT><<<dim3(IN_DIM / 64, NB / 64), 256, 0, stream>>>(
        xbf, WTbf, nullptr, out, nullptr, NB, IN_DIM, OUT_DIM);
}

// Round 3
// 1016.446 us; speedup vs baseline: 6.2545x; 1.3724x over previous
//
#include <hip/hip_runtime.h>
#include <math.h>

// Sparse2L, bf16-MFMA version, round 3: bf16-only x state, pool fused into XUP.
//  per step: R = x@W - inputs; z = u@V; cbf=(1+e^-z)/2; dcbf=-e^-z/2;
//            x = softthr(x - 2lr*(R@W^T), lr*gamma*up(cbf));   [x carried in bf16]
//            gin = dcbf * maxpool2x2(x) * gamma    (fused into XUP epilogue);
//            u = softthr(u - lr*(gin@V^T), lr*gamma/10)
//  output = x9 @ W
// GEMM: A [M][K] bf16 row-major, B stored B^T-layout [N][K] bf16, MFMA 16x16x32.
// LDS tiles [rows][64] bf16 with seg^(row&7) XOR swizzle on BOTH global_load_lds
// source and ds_read_b128 (rule 21); verified round 2: bank conflicts = 0.

#define NB 4096
#define IN_DIM 512
#define OUT_DIM 4096
#define CAUSES_DIM 256
#define POOLED_DIM 1024

typedef __attribute__((ext_vector_type(8))) short short8;
typedef __attribute__((ext_vector_type(4))) float f32x4;

static constexpr float LR = 0.001f;
static constexpr float GAMMA = 0.1f;

enum { EP_R = 0, EP_OUT, EP_CAUSES, EP_XUP, EP_XUP_LAST, EP_UUP };

__device__ __forceinline__ float softthr(float v, float t) {
    return fmaxf(v - t, 0.0f) + fminf(v + t, 0.0f);
}
__device__ __forceinline__ unsigned short f2bf(float f) {
    unsigned int u = __builtin_bit_cast(unsigned int, f);
    u = (u + 0x7fffu + ((u >> 16) & 1u)) >> 16;
    return (unsigned short)u;
}
__device__ __forceinline__ float bf2f(unsigned short h) {
    return __builtin_bit_cast(float, (unsigned int)h << 16);
}
__device__ __forceinline__ void gload_lds16(const unsigned short* g, unsigned short* l) {
    __builtin_amdgcn_global_load_lds(
        (const __attribute__((address_space(1))) void*)g,
        (__attribute__((address_space(3))) void*)l, 16, 0, 0);
}

// ---------------------------------------------------------------------------
// bf16 MFMA GEMM, 256 threads = 4 waves (2x2), BK=64, per-wave BM/2 x BN/2.
// ---------------------------------------------------------------------------
template<int BM, int BN, int EP>
__global__ __launch_bounds__(256)
void gemm_bf16(const unsigned short* __restrict__ A, const unsigned short* __restrict__ B,
               const float* __restrict__ auxf,          // EP_R: inputs f32
               const unsigned short* __restrict__ cbf,  // EP_XUP*: causes bf16
               const unsigned short* __restrict__ dcbf, // EP_XUP: dc bf16
               void* __restrict__ out0, void* __restrict__ out1,
               int M, int N, int K)
{
    constexpr int WM = BM / 2, WN = BN / 2;
    constexpr int FM = WM / 16, FN = WN / 16;
    constexpr bool POOLF = (EP == EP_XUP);   // fused pool+gin
    constexpr int BASE_SHORTS = (BM + BN) * 64;
    constexpr int XS_SHORTS = 128 * 130;     // padded x tile for pool phase
    constexpr int LDS_SHORTS =
        (POOLF && XS_SHORTS > BASE_SHORTS) ? XS_SHORTS : BASE_SHORTS;
    __shared__ unsigned short lds[LDS_SHORTS];
    unsigned short* As = lds;
    unsigned short* Bs = lds + BM * 64;
    unsigned short* xs = lds;                // reused after K loop (POOLF only)

    const int t    = threadIdx.x;
    const int lane = t & 63, wid = t >> 6;
    const int l15  = lane & 15, l7 = lane & 7, g = lane >> 4;
    const int m0 = blockIdx.y * BM, n0 = blockIdx.x * BN;
    const int wm0 = (wid >> 1) * WM, wn0 = (wid & 1) * WN;

    f32x4 acc[FM][FN];
#pragma unroll
    for (int fi = 0; fi < FM; fi++)
#pragma unroll
        for (int fj = 0; fj < FN; fj++) acc[fi][fj] = (f32x4){0.f, 0.f, 0.f, 0.f};

    for (int k0 = 0; k0 < K; k0 += 64) {
#pragma unroll
        for (int j = 0; j < BM / 32; j++) {
            const int idx = j * 256 + t;
            const int row = idx >> 3;
            const int sl  = (idx & 7) ^ (row & 7);
            gload_lds16(A + (size_t)(m0 + row) * K + k0 + sl * 8,
                        As + (size_t)(idx & ~63) * 8);
        }
#pragma unroll
        for (int j = 0; j < BN / 32; j++) {
            const int idx = j * 256 + t;
            const int row = idx >> 3;
            const int sl  = (idx & 7) ^ (row & 7);
            gload_lds16(B + (size_t)(n0 + row) * K + k0 + sl * 8,
                        Bs + (size_t)(idx & ~63) * 8);
        }
        __syncthreads();

#pragma unroll
        for (int ks = 0; ks < 2; ks++) {
            const int so = (((ks * 4) + g) ^ l7) * 8;
            short8 af[FM], bfv[FN];
#pragma unroll
            for (int fi = 0; fi < FM; fi++)
                af[fi] = *(const short8*)&As[(wm0 + fi * 16 + l15) * 64 + so];
#pragma unroll
            for (int fj = 0; fj < FN; fj++)
                bfv[fj] = *(const short8*)&Bs[(wn0 + fj * 16 + l15) * 64 + so];
#pragma unroll
            for (int fi = 0; fi < FM; fi++)
#pragma unroll
                for (int fj = 0; fj < FN; fj++)
                    acc[fi][fj] = __builtin_amdgcn_mfma_f32_16x16x32_bf16(
                        af[fi], bfv[fj], acc[fi][fj], 0, 0, 0);
        }
        __syncthreads();
    }

    // ---- epilogue ----
#pragma unroll
    for (int fi = 0; fi < FM; fi++) {
#pragma unroll
        for (int fj = 0; fj < FN; fj++) {
#pragma unroll
            for (int r = 0; r < 4; r++) {
                const int row = m0 + wm0 + fi * 16 + g * 4 + r;
                const int col = n0 + wn0 + fj * 16 + l15;
                const float v = acc[fi][fj][r];
                if (EP == EP_R) {
                    ((unsigned short*)out0)[(size_t)row * N + col] =
                        f2bf(v - auxf[(size_t)row * N + col]);
                } else if (EP == EP_OUT) {
                    ((float*)out0)[(size_t)row * N + col] = v;
                } else if (EP == EP_CAUSES) {
                    const float e = expf(-v);
                    ((unsigned short*)out0)[(size_t)row * N + col] = f2bf(0.5f + 0.5f * e);
                    ((unsigned short*)out1)[(size_t)row * N + col] = f2bf(-0.5f * e);
                } else if (EP == EP_XUP || EP == EP_XUP_LAST) {
                    const int pcol = (col & 63) >> 1;          // pooled col 0..31
                    const float cz = bf2f(cbf[(size_t)row * POOLED_DIM +
                                              blockIdx.x * 32 + pcol]);
                    unsigned short* xbf = (unsigned short*)out0;
                    const size_t idx = (size_t)row * OUT_DIM + col;
                    const float xold = bf2f(xbf[idx]);
                    const float xv = softthr(xold - 2.0f * LR * v, LR * GAMMA * cz);
                    const unsigned short xq = f2bf(xv);
                    xbf[idx] = xq;
                    if (POOLF) {
                        const int rloc = wm0 + fi * 16 + g * 4 + r;
                        const int cloc = wn0 + fj * 16 + l15;
                        xs[rloc * 130 + cloc] = xq;
                    }
                } else { // EP_UUP
                    float* up = (float*)out0;
                    const size_t idx = (size_t)row * CAUSES_DIM + col;
                    const float uv = softthr(up[idx] - LR * v, LR * GAMMA * 0.1f);
                    up[idx] = uv;
                    ((unsigned short*)out1)[idx] = f2bf(uv);
                }
            }
        }
    }

    // ---- fused maxpool2x2 + gin (XUP only, not last step) ----
    if (POOLF) {
        __syncthreads();
        const int prow = t & 127;     // local row
        const int half = t >> 7;      // 0/1 -> pooled cols [0,16) / [16,32)
        const size_t gp = (size_t)(m0 + prow) * POOLED_DIM + blockIdx.x * 32 + half * 16;
        short8 dc0 = *(const short8*)&dcbf[gp];
        short8 dc1 = *(const short8*)&dcbf[gp + 8];
        unsigned short res[16];
#pragma unroll
        for (int i = 0; i < 16; i++) {
            const int pc = half * 16 + i;                 // local pooled col 0..31
            const unsigned short* xr = &xs[prow * 130 + 2 * pc];
            const float mx = fmaxf(fmaxf(bf2f(xr[0]), bf2f(xr[1])),
                                   fmaxf(bf2f(xr[64]), bf2f(xr[65])));
            const float dcv = bf2f((unsigned short)(i < 8 ? dc0[i] : dc1[i - 8]));
            res[i] = f2bf(dcv * mx * GAMMA);
        }
        unsigned short* gbf = (unsigned short*)out1;
        *(short8*)&gbf[gp]     = *(const short8*)&res[0];
        *(short8*)&gbf[gp + 8] = *(const short8*)&res[8];
    }
}

// ---------------------------------------------------------------------------
// setup kernels
// ---------------------------------------------------------------------------
__global__ void cast_bf16_k(const float* __restrict__ in, unsigned short* __restrict__ out,
                            int n4, int neg)
{
    const int i = blockIdx.x * 256 + threadIdx.x;
    if (i >= n4) return;
    float4 v = ((const float4*)in)[i];
    if (neg) { v.x = -v.x; v.y = -v.y; v.z = -v.z; v.w = -v.w; }
    union { unsigned short s[4]; unsigned long long u; } p;
    p.s[0] = f2bf(v.x); p.s[1] = f2bf(v.y); p.s[2] = f2bf(v.z); p.s[3] = f2bf(v.w);
    ((unsigned long long*)out)[i] = p.u;
}

// transpose+cast: f32 in[R][C] -> bf16 out[C][R]
__global__ __launch_bounds__(256)
void transpose_cast_k(const float* __restrict__ in, unsigned short* __restrict__ out,
                      int R, int C)
{
    __shared__ float tile[32][33];
    const int bx = blockIdx.x * 32, by = blockIdx.y * 32;
    const int tx = threadIdx.x % 32, ty = threadIdx.x / 32;
#pragma unroll
    for (int i = 0; i < 32; i += 8)
        tile[ty + i][tx] = in[(size_t)(by + ty + i) * C + bx + tx];
    __syncthreads();
#pragma unroll
    for (int i = 0; i < 32; i += 8)
        out[(size_t)(bx + ty + i) * R + by + tx] = f2bf(tile[tx][ty + i]);
}

__global__ void fill_zero_u16(unsigned short* __restrict__ p, size_t n8) {
    for (size_t i = (size_t)blockIdx.x * 256 + threadIdx.x; i < n8;
         i += (size_t)gridDim.x * 256)
        ((ulonglong2*)p)[i] = (ulonglong2){0ull, 0ull};
}

__global__ void fill_u_k(float* __restrict__ u, unsigned short* __restrict__ ubf, int n) {
    const int i = blockIdx.x * 256 + threadIdx.x;
    if (i >= n) return;
    u[i] = 0.1f;
    ubf[i] = f2bf(0.1f);
}

extern "C" void kernel_launch(void* const* d_in, const int* in_sizes, int n_in,
                              void* d_out, int out_size, void* d_ws, size_t ws_size,
                              hipStream_t stream)
{
    const float* inputs = (const float*)d_in[0];   // [4096, 512]
    const float* W      = (const float*)d_in[1];   // [4096, 512]
    const float* V      = (const float*)d_in[2];   // [256, 1024]
    float* out = (float*)d_out;                    // [4096, 512]

    // workspace (~75 MB)
    char* w = (char*)d_ws;
    unsigned short* xbf  = (unsigned short*)w; w += (size_t)NB * OUT_DIM * 2;       // 32 MB
    unsigned short* Rbf  = (unsigned short*)w; w += (size_t)NB * IN_DIM * 2;        //  4 MB
    unsigned short* cbf  = (unsigned short*)w; w += (size_t)NB * POOLED_DIM * 2;    //  8 MB
    unsigned short* dcbf = (unsigned short*)w; w += (size_t)NB * POOLED_DIM * 2;    //  8 MB
    unsigned short* gbf  = (unsigned short*)w; w += (size_t)NB * POOLED_DIM * 2;    //  8 MB
    float*          u    = (float*)w;          w += (size_t)NB * CAUSES_DIM * 4;    //  4 MB
    unsigned short* ubf  = (unsigned short*)w; w += (size_t)NB * CAUSES_DIM * 2;    //  2 MB
    unsigned short* Wbf  = (unsigned short*)w; w += (size_t)OUT_DIM * IN_DIM * 2;   //  4 MB
    unsigned short* WTbf = (unsigned short*)w; w += (size_t)OUT_DIM * IN_DIM * 2;   //  4 MB
    unsigned short* Vbf  = (unsigned short*)w; w += (size_t)CAUSES_DIM * POOLED_DIM * 2;
    unsigned short* VTbf = (unsigned short*)w;

    // ---- setup ----
    cast_bf16_k<<<OUT_DIM * IN_DIM / 4 / 256, 256, 0, stream>>>(W, Wbf, OUT_DIM * IN_DIM / 4, 0);
    cast_bf16_k<<<CAUSES_DIM * POOLED_DIM / 4 / 256, 256, 0, stream>>>(V, Vbf, CAUSES_DIM * POOLED_DIM / 4, 0);
    transpose_cast_k<<<dim3(IN_DIM / 32, OUT_DIM / 32), 256, 0, stream>>>(W, WTbf, OUT_DIM, IN_DIM);
    transpose_cast_k<<<dim3(POOLED_DIM / 32, CAUSES_DIM / 32), 256, 0, stream>>>(V, VTbf, CAUSES_DIM, POOLED_DIM);
    fill_zero_u16<<<2048, 256, 0, stream>>>(xbf, (size_t)NB * OUT_DIM / 8);
    fill_u_k<<<NB * CAUSES_DIM / 256, 256, 0, stream>>>(u, ubf, NB * CAUSES_DIM);
    cast_bf16_k<<<NB * IN_DIM / 4 / 256, 256, 0, stream>>>(inputs, Rbf, NB * IN_DIM / 4, 1); // R0=-inputs

    for (int t = 0; t < 9; t++) {
        if (t > 0) {
            // Rbf = bf16(x@W - inputs)
            gemm_bf16<64, 64, EP_R><<<dim3(IN_DIM / 64, NB / 64), 256, 0, stream>>>(
                xbf, WTbf, inputs, nullptr, nullptr, Rbf, nullptr, NB, IN_DIM, OUT_DIM);
        }
        // cbf/dcbf from z = u@V
        gemm_bf16<64, 64, EP_CAUSES><<<dim3(POOLED_DIM / 64, NB / 64), 256, 0, stream>>>(
            ubf, VTbf, nullptr, nullptr, nullptr, cbf, dcbf, NB, POOLED_DIM, CAUSES_DIM);
        // x = softthr(x - 2lr*(R@W^T), lr*g*up(cbf)); fused pool -> gbf (except last)
        if (t < 8) {
            gemm_bf16<128, 128, EP_XUP><<<dim3(OUT_DIM / 128, NB / 128), 256, 0, stream>>>(
                Rbf, Wbf, nullptr, cbf, dcbf, xbf, gbf, NB, OUT_DIM, IN_DIM);
            // u = softthr(u - lr*(gin@V^T), lr*g/10)
            gemm_bf16<64, 64, EP_UUP><<<dim3(CAUSES_DIM / 64, NB / 64), 256, 0, stream>>>(
                gbf, Vbf, nullptr, nullptr, nullptr, u, ubf, NB, CAUSES_DIM, POOLED_DIM);
        } else {
            gemm_bf16<128, 128, EP_XUP_LAST><<<dim3(OUT_DIM / 128, NB / 128), 256, 0, stream>>>(
                Rbf, Wbf, nullptr, cbf, nullptr, xbf, nullptr, NB, OUT_DIM, IN_DIM);
        }
    }
    // rec = x9 @ W
    gemm_bf16<64, 64, EP_OUT><<<dim3(IN_DIM / 64, NB / 64), 256, 0, stream>>>(
        xbf, WTbf, nullptr, nullptr, nullptr, out, nullptr, NB, IN_DIM, OUT_DIM);
}

// Round 4
// 843.152 us; speedup vs baseline: 7.5400x; 1.2055x over previous
//
#include <hip/hip_runtime.h>
#include <math.h>

// Sparse2L round 4: T3-minimum double-buffered prefetch pipeline + XCD-chunked
// blockIdx swizzle; all GEMM dims compile-time.
//  per step: R = x@W - inputs; z = u@V; cbf=(1+e^-z)/2; dcbf=-e^-z/2;
//            x = softthr(x - 2lr*(R@W^T), lr*gamma*up(cbf));   [x in bf16]
//            gin = dcbf * maxpool2x2(x) * gamma   (fused in XUP epilogue);
//            u = softthr(u - lr*(gin@V^T), lr*gamma/10)
//  output = x9 @ W
// GEMM: A [M][K] bf16 row-major, B stored B^T-layout [N][K] bf16, MFMA 16x16x32.
// LDS tiles [rows][64] bf16, seg^(row&7) XOR swizzle on BOTH global_load_lds
// source and ds_read_b128 (verified: SQ_LDS_BANK_CONFLICT == 0).

#define NB 4096
#define IN_DIM 512
#define OUT_DIM 4096
#define CAUSES_DIM 256
#define POOLED_DIM 1024

typedef __attribute__((ext_vector_type(8))) short short8;
typedef __attribute__((ext_vector_type(4))) float f32x4;

static constexpr float LR = 0.001f;
static constexpr float GAMMA = 0.1f;

enum { EP_R = 0, EP_OUT, EP_CAUSES, EP_XUP, EP_XUP_LAST, EP_UUP };

__device__ __forceinline__ float softthr(float v, float t) {
    return fmaxf(v - t, 0.0f) + fminf(v + t, 0.0f);
}
__device__ __forceinline__ unsigned short f2bf(float f) {
    unsigned int u = __builtin_bit_cast(unsigned int, f);
    u = (u + 0x7fffu + ((u >> 16) & 1u)) >> 16;
    return (unsigned short)u;
}
__device__ __forceinline__ float bf2f(unsigned short h) {
    return __builtin_bit_cast(float, (unsigned int)h << 16);
}
__device__ __forceinline__ void gload_lds16(const unsigned short* g, unsigned short* l) {
    __builtin_amdgcn_global_load_lds(
        (const __attribute__((address_space(1))) void*)g,
        (__attribute__((address_space(3))) void*)l, 16, 0, 0);
}

// ---------------------------------------------------------------------------
// bf16 MFMA GEMM, 256 threads = 4 waves (2x2), BK=64, double-buffered LDS with
// prefetch-before-compute (one barrier per K-step). M fixed = NB.
// ---------------------------------------------------------------------------
template<int BM, int BN, int N, int K, int EP>
__global__ __launch_bounds__(256)
void gemm_bf16(const unsigned short* __restrict__ A, const unsigned short* __restrict__ B,
               const float* __restrict__ auxf,          // EP_R: inputs f32
               const unsigned short* __restrict__ cbf,  // EP_XUP*: causes bf16
               const unsigned short* __restrict__ dcbf, // EP_XUP: dcauses bf16
               void* __restrict__ out0, void* __restrict__ out1)
{
    constexpr int WM = BM / 2, WN = BN / 2;
    constexpr int FM = WM / 16, FN = WN / 16;
    constexpr int NK = K / 64;
    constexpr int NX = N / BN;
    constexpr int NWG = (NB / BM) * NX;
    constexpr bool POOLF = (EP == EP_XUP);
    constexpr int TILE = (BM + BN) * 64;          // shorts per buffer
    constexpr int XS_SHORTS = 128 * 130;
    constexpr int LDS_SHORTS =
        (POOLF && XS_SHORTS > 2 * TILE) ? XS_SHORTS : 2 * TILE;
    __shared__ unsigned short lds[LDS_SHORTS];
    unsigned short* A0 = lds;
    unsigned short* B0 = lds + BM * 64;
    unsigned short* A1 = lds + TILE;
    unsigned short* B1 = lds + TILE + BM * 64;
    unsigned short* xs = lds;                     // pool reuse (POOLF)

    const int t    = threadIdx.x;
    const int lane = t & 63, wid = t >> 6;
    const int l15  = lane & 15, l7 = lane & 7, g = lane >> 4;
    // XCD-chunked bijective swizzle (NWG % 8 == 0): each XCD gets a contiguous
    // work-chunk; n-fastest decode -> same-XCD blocks share the A m-panel.
    const int work = ((blockIdx.x & 7) * (NWG / 8)) + (blockIdx.x >> 3);
    const int bn = work % NX, bm = work / NX;
    const int m0 = bm * BM, n0 = bn * BN;
    const int wm0 = (wid >> 1) * WM, wn0 = (wid & 1) * WN;

    f32x4 acc[FM][FN];
#pragma unroll
    for (int fi = 0; fi < FM; fi++)
#pragma unroll
        for (int fj = 0; fj < FN; fj++) acc[fi][fj] = (f32x4){0.f, 0.f, 0.f, 0.f};

    auto stage = [&](unsigned short* As, unsigned short* Bs, int k0) {
#pragma unroll
        for (int j = 0; j < BM / 32; j++) {
            const int idx = j * 256 + t;
            const int row = idx >> 3;
            const int sl  = (idx & 7) ^ (row & 7);
            gload_lds16(A + (size_t)(m0 + row) * K + k0 + sl * 8,
                        As + (size_t)(idx & ~63) * 8);
        }
#pragma unroll
        for (int j = 0; j < BN / 32; j++) {
            const int idx = j * 256 + t;
            const int row = idx >> 3;
            const int sl  = (idx & 7) ^ (row & 7);
            gload_lds16(B + (size_t)(n0 + row) * K + k0 + sl * 8,
                        Bs + (size_t)(idx & ~63) * 8);
        }
    };
    auto compute = [&](const unsigned short* As, const unsigned short* Bs) {
#pragma unroll
        for (int ks = 0; ks < 2; ks++) {
            const int so = (((ks * 4) + g) ^ l7) * 8;
            short8 af[FM], bfv[FN];
#pragma unroll
            for (int fi = 0; fi < FM; fi++)
                af[fi] = *(const short8*)&As[(wm0 + fi * 16 + l15) * 64 + so];
#pragma unroll
            for (int fj = 0; fj < FN; fj++)
                bfv[fj] = *(const short8*)&Bs[(wn0 + fj * 16 + l15) * 64 + so];
#pragma unroll
            for (int fi = 0; fi < FM; fi++)
#pragma unroll
                for (int fj = 0; fj < FN; fj++)
                    acc[fi][fj] = __builtin_amdgcn_mfma_f32_16x16x32_bf16(
                        af[fi], bfv[fj], acc[fi][fj], 0, 0, 0);
        }
    };

    // prologue
    stage(A0, B0, 0);
    __syncthreads();
    // main pipeline: prefetch next K-tile, then compute current; 1 barrier/K-step
#pragma unroll 1
    for (int kt = 0; kt < NK; kt += 2) {
        stage(A1, B1, (kt + 1) * 64);
        compute(A0, B0);
        __syncthreads();
        if (kt + 2 < NK) stage(A0, B0, (kt + 2) * 64);
        compute(A1, B1);
        __syncthreads();
    }

    // ---- epilogue ----
#pragma unroll
    for (int fi = 0; fi < FM; fi++) {
#pragma unroll
        for (int fj = 0; fj < FN; fj++) {
#pragma unroll
            for (int r = 0; r < 4; r++) {
                const int row = m0 + wm0 + fi * 16 + g * 4 + r;
                const int col = n0 + wn0 + fj * 16 + l15;
                const float v = acc[fi][fj][r];
                if (EP == EP_R) {
                    ((unsigned short*)out0)[(size_t)row * N + col] =
                        f2bf(v - auxf[(size_t)row * N + col]);
                } else if (EP == EP_OUT) {
                    ((float*)out0)[(size_t)row * N + col] = v;
                } else if (EP == EP_CAUSES) {
                    const float e = expf(-v);
                    ((unsigned short*)out0)[(size_t)row * N + col] = f2bf(0.5f + 0.5f * e);
                    ((unsigned short*)out1)[(size_t)row * N + col] = f2bf(-0.5f * e);
                } else if (EP == EP_XUP || EP == EP_XUP_LAST) {
                    const int pcol = (col & 63) >> 1;
                    const float cz = bf2f(cbf[(size_t)row * POOLED_DIM + bn * 32 + pcol]);
                    unsigned short* xbf = (unsigned short*)out0;
                    const size_t idx = (size_t)row * OUT_DIM + col;
                    const float xold = bf2f(xbf[idx]);
                    const float xv = softthr(xold - 2.0f * LR * v, LR * GAMMA * cz);
                    const unsigned short xq = f2bf(xv);
                    xbf[idx] = xq;
                    if (POOLF) {
                        const int rloc = wm0 + fi * 16 + g * 4 + r;
                        const int cloc = wn0 + fj * 16 + l15;
                        xs[rloc * 130 + cloc] = xq;
                    }
                } else { // EP_UUP
                    float* up = (float*)out0;
                    const size_t idx = (size_t)row * CAUSES_DIM + col;
                    const float uv = softthr(up[idx] - LR * v, LR * GAMMA * 0.1f);
                    up[idx] = uv;
                    ((unsigned short*)out1)[idx] = f2bf(uv);
                }
            }
        }
    }

    // ---- fused maxpool2x2 + gin (XUP only, not last step) ----
    if (POOLF) {
        __syncthreads();
        const int prow = t & 127;
        const int half = t >> 7;
        const size_t gp = (size_t)(m0 + prow) * POOLED_DIM + bn * 32 + half * 16;
        short8 dc0 = *(const short8*)&dcbf[gp];
        short8 dc1 = *(const short8*)&dcbf[gp + 8];
        unsigned short res[16];
#pragma unroll
        for (int i = 0; i < 16; i++) {
            const int pc = half * 16 + i;
            const unsigned short* xr = &xs[prow * 130 + 2 * pc];
            const float mx = fmaxf(fmaxf(bf2f(xr[0]), bf2f(xr[1])),
                                   fmaxf(bf2f(xr[64]), bf2f(xr[65])));
            const float dcv = bf2f((unsigned short)(i < 8 ? dc0[i] : dc1[i - 8]));
            res[i] = f2bf(dcv * mx * GAMMA);
        }
        unsigned short* gbf = (unsigned short*)out1;
        *(short8*)&gbf[gp]     = *(const short8*)&res[0];
        *(short8*)&gbf[gp + 8] = *(const short8*)&res[8];
    }
}

// ---------------------------------------------------------------------------
// setup kernels
// ---------------------------------------------------------------------------
__global__ void cast_bf16_k(const float* __restrict__ in, unsigned short* __restrict__ out,
                            int n4, int neg)
{
    const int i = blockIdx.x * 256 + threadIdx.x;
    if (i >= n4) return;
    float4 v = ((const float4*)in)[i];
    if (neg) { v.x = -v.x; v.y = -v.y; v.z = -v.z; v.w = -v.w; }
    union { unsigned short s[4]; unsigned long long u; } p;
    p.s[0] = f2bf(v.x); p.s[1] = f2bf(v.y); p.s[2] = f2bf(v.z); p.s[3] = f2bf(v.w);
    ((unsigned long long*)out)[i] = p.u;
}

// transpose+cast: f32 in[R][C] -> bf16 out[C][R]
__global__ __launch_bounds__(256)
void transpose_cast_k(const float* __restrict__ in, unsigned short* __restrict__ out,
                      int R, int C)
{
    __shared__ float tile[32][33];
    const int bx = blockIdx.x * 32, by = blockIdx.y * 32;
    const int tx = threadIdx.x % 32, ty = threadIdx.x / 32;
#pragma unroll
    for (int i = 0; i < 32; i += 8)
        tile[ty + i][tx] = in[(size_t)(by + ty + i) * C + bx + tx];
    __syncthreads();
#pragma unroll
    for (int i = 0; i < 32; i += 8)
        out[(size_t)(bx + ty + i) * R + by + tx] = f2bf(tile[tx][ty + i]);
}

__global__ void fill_zero_u16(unsigned short* __restrict__ p, size_t n8) {
    for (size_t i = (size_t)blockIdx.x * 256 + threadIdx.x; i < n8;
         i += (size_t)gridDim.x * 256)
        ((ulonglong2*)p)[i] = (ulonglong2){0ull, 0ull};
}

__global__ void fill_u_k(float* __restrict__ u, unsigned short* __restrict__ ubf, int n) {
    const int i = blockIdx.x * 256 + threadIdx.x;
    if (i >= n) return;
    u[i] = 0.1f;
    ubf[i] = f2bf(0.1f);
}

extern "C" void kernel_launch(void* const* d_in, const int* in_sizes, int n_in,
                              void* d_out, int out_size, void* d_ws, size_t ws_size,
                              hipStream_t stream)
{
    const float* inputs = (const float*)d_in[0];   // [4096, 512]
    const float* W      = (const float*)d_in[1];   // [4096, 512]
    const float* V      = (const float*)d_in[2];   // [256, 1024]
    float* out = (float*)d_out;                    // [4096, 512]

    // workspace (~75 MB)
    char* w = (char*)d_ws;
    unsigned short* xbf  = (unsigned short*)w; w += (size_t)NB * OUT_DIM * 2;
    unsigned short* Rbf  = (unsigned short*)w; w += (size_t)NB * IN_DIM * 2;
    unsigned short* cbf  = (unsigned short*)w; w += (size_t)NB * POOLED_DIM * 2;
    unsigned short* dcbf = (unsigned short*)w; w += (size_t)NB * POOLED_DIM * 2;
    unsigned short* gbf  = (unsigned short*)w; w += (size_t)NB * POOLED_DIM * 2;
    float*          u    = (float*)w;          w += (size_t)NB * CAUSES_DIM * 4;
    unsigned short* ubf  = (unsigned short*)w; w += (size_t)NB * CAUSES_DIM * 2;
    unsigned short* Wbf  = (unsigned short*)w; w += (size_t)OUT_DIM * IN_DIM * 2;
    unsigned short* WTbf = (unsigned short*)w; w += (size_t)OUT_DIM * IN_DIM * 2;
    unsigned short* Vbf  = (unsigned short*)w; w += (size_t)CAUSES_DIM * POOLED_DIM * 2;
    unsigned short* VTbf = (unsigned short*)w;

    // ---- setup ----
    cast_bf16_k<<<OUT_DIM * IN_DIM / 4 / 256, 256, 0, stream>>>(W, Wbf, OUT_DIM * IN_DIM / 4, 0);
    cast_bf16_k<<<CAUSES_DIM * POOLED_DIM / 4 / 256, 256, 0, stream>>>(V, Vbf, CAUSES_DIM * POOLED_DIM / 4, 0);
    transpose_cast_k<<<dim3(IN_DIM / 32, OUT_DIM / 32), 256, 0, stream>>>(W, WTbf, OUT_DIM, IN_DIM);
    transpose_cast_k<<<dim3(POOLED_DIM / 32, CAUSES_DIM / 32), 256, 0, stream>>>(V, VTbf, CAUSES_DIM, POOLED_DIM);
    fill_zero_u16<<<2048, 256, 0, stream>>>(xbf, (size_t)NB * OUT_DIM / 8);
    fill_u_k<<<NB * CAUSES_DIM / 256, 256, 0, stream>>>(u, ubf, NB * CAUSES_DIM);
    cast_bf16_k<<<NB * IN_DIM / 4 / 256, 256, 0, stream>>>(inputs, Rbf, NB * IN_DIM / 4, 1); // R0=-inputs

    for (int t = 0; t < 9; t++) {
        if (t > 0) {
            // Rbf = bf16(x@W - inputs)
            gemm_bf16<64, 64, IN_DIM, OUT_DIM, EP_R><<<512, 256, 0, stream>>>(
                xbf, WTbf, inputs, nullptr, nullptr, Rbf, nullptr);
        }
        // cbf/dcbf from z = u@V
        gemm_bf16<64, 64, POOLED_DIM, CAUSES_DIM, EP_CAUSES><<<1024, 256, 0, stream>>>(
            ubf, VTbf, nullptr, nullptr, nullptr, cbf, dcbf);
        if (t < 8) {
            // x-update + fused pool -> gbf
            gemm_bf16<128, 128, OUT_DIM, IN_DIM, EP_XUP><<<1024, 256, 0, stream>>>(
                Rbf, Wbf, nullptr, cbf, dcbf, xbf, gbf);
            // u = softthr(u - lr*(gin@V^T), lr*g/10)
            gemm_bf16<64, 64, CAUSES_DIM, POOLED_DIM, EP_UUP><<<256, 256, 0, stream>>>(
                gbf, Vbf, nullptr, nullptr, nullptr, u, ubf);
        } else {
            gemm_bf16<128, 128, OUT_DIM, IN_DIM, EP_XUP_LAST><<<1024, 256, 0, stream>>>(
                Rbf, Wbf, nullptr, cbf, nullptr, xbf, nullptr);
        }
    }
    // rec = x9 @ W
    gemm_bf16<64, 64, IN_DIM, OUT_DIM, EP_OUT><<<512, 256, 0, stream>>>(
        xbf, WTbf, nullptr, nullptr, nullptr, out, nullptr);
}

// Round 5
// 795.219 us; speedup vs baseline: 7.9944x; 1.0603x over previous
//
#include <hip/hip_runtime.h>
#include <math.h>

// Sparse2L round 5: fuse causes-GEMM into XUP (XUPC), horizontal-fuse UUP+R,
// retile K=4096 GEMMs to 128x64. 25 launches total.
//  per step: R = x@W - inputs; z = u@V (mini-GEMM inside XUPC);
//            x = softthr(x - 2lr*(R@W^T), lr*gamma*up((1+e^-z)/2));  [x bf16]
//            gin = (-e^-z/2) * maxpool2x2(x) * gamma  (fused pool phase);
//            u = softthr(u - lr*(gin@V^T), lr*gamma/10)   [in H kernel]
//  output = x9 @ W
// GEMM: A [M][K] bf16 row-major, B in B^T layout [N][K] bf16, MFMA 16x16x32.
// LDS tiles [rows][64] bf16, seg^(row&7) XOR swizzle on BOTH global_load_lds
// source and ds_read_b128 (verified: SQ_LDS_BANK_CONFLICT == 0).

#define NB 4096
#define IN_DIM 512
#define OUT_DIM 4096
#define CAUSES_DIM 256
#define POOLED_DIM 1024

typedef __attribute__((ext_vector_type(8))) short short8;
typedef __attribute__((ext_vector_type(4))) float f32x4;

static constexpr float LR = 0.001f;
static constexpr float GAMMA = 0.1f;

enum { EP_R = 0, EP_OUT, EP_UUP };

__device__ __forceinline__ float softthr(float v, float t) {
    return fmaxf(v - t, 0.0f) + fminf(v + t, 0.0f);
}
__device__ __forceinline__ unsigned short f2bf(float f) {
    unsigned int u = __builtin_bit_cast(unsigned int, f);
    u = (u + 0x7fffu + ((u >> 16) & 1u)) >> 16;
    return (unsigned short)u;
}
__device__ __forceinline__ float bf2f(unsigned short h) {
    return __builtin_bit_cast(float, (unsigned int)h << 16);
}
__device__ __forceinline__ void gload_lds16(const unsigned short* g, unsigned short* l) {
    __builtin_amdgcn_global_load_lds(
        (const __attribute__((address_space(1))) void*)g,
        (__attribute__((address_space(3))) void*)l, 16, 0, 0);
}

// stage ROWS x 64 bf16 tile; linear LDS dest, inverse-swizzled global source.
template<int ROWS, int K>
__device__ __forceinline__ void stage_tile(const unsigned short* __restrict__ g,
                                           unsigned short* l, int row0, int k0, int t)
{
#pragma unroll
    for (int j = 0; j < ROWS / 32; j++) {
        const int idx = j * 256 + t;
        const int row = idx >> 3;
        const int sl  = (idx & 7) ^ (row & 7);
        gload_lds16(g + (size_t)(row0 + row) * K + k0 + sl * 8,
                    l + (size_t)(idx & ~63) * 8);
    }
}

// ---------------------------------------------------------------------------
// generic GEMM core (EP_R / EP_OUT / EP_UUP), 4 waves 2x2, BK=64 double-buffer
// ---------------------------------------------------------------------------
template<int BM, int BN, int N, int K, int EP>
__device__ void gemm_core(unsigned short* lds, int bid,
                          const unsigned short* __restrict__ A,
                          const unsigned short* __restrict__ B,
                          const float* __restrict__ auxf,
                          void* __restrict__ out0, void* __restrict__ out1)
{
    constexpr int WM = BM / 2, WN = BN / 2;
    constexpr int FM = WM / 16, FN = WN / 16;
    constexpr int NK = K / 64, NX = N / BN;
    constexpr int NWG = (NB / BM) * NX;
    constexpr int TILE = (BM + BN) * 64;
    unsigned short* A0 = lds;
    unsigned short* B0 = lds + BM * 64;
    unsigned short* A1 = lds + TILE;
    unsigned short* B1 = lds + TILE + BM * 64;

    const int t    = threadIdx.x;
    const int lane = t & 63, wid = t >> 6;
    const int l15  = lane & 15, l7 = lane & 7, g = lane >> 4;
    const int work = ((bid & 7) * (NWG / 8)) + (bid >> 3);
    const int bn = work % NX, bm = work / NX;
    const int m0 = bm * BM, n0 = bn * BN;
    const int wm0 = (wid >> 1) * WM, wn0 = (wid & 1) * WN;

    f32x4 acc[FM][FN];
#pragma unroll
    for (int fi = 0; fi < FM; fi++)
#pragma unroll
        for (int fj = 0; fj < FN; fj++) acc[fi][fj] = (f32x4){0.f, 0.f, 0.f, 0.f};

    auto compute = [&](const unsigned short* As, const unsigned short* Bs) {
#pragma unroll
        for (int ks = 0; ks < 2; ks++) {
            const int so = (((ks * 4) + g) ^ l7) * 8;
            short8 af[FM], bfv[FN];
#pragma unroll
            for (int fi = 0; fi < FM; fi++)
                af[fi] = *(const short8*)&As[(wm0 + fi * 16 + l15) * 64 + so];
#pragma unroll
            for (int fj = 0; fj < FN; fj++)
                bfv[fj] = *(const short8*)&Bs[(wn0 + fj * 16 + l15) * 64 + so];
#pragma unroll
            for (int fi = 0; fi < FM; fi++)
#pragma unroll
                for (int fj = 0; fj < FN; fj++)
                    acc[fi][fj] = __builtin_amdgcn_mfma_f32_16x16x32_bf16(
                        af[fi], bfv[fj], acc[fi][fj], 0, 0, 0);
        }
    };

    stage_tile<BM, K>(A, A0, m0, 0, t);
    stage_tile<BN, K>(B, B0, n0, 0, t);
    __syncthreads();
#pragma unroll 1
    for (int kt = 0; kt < NK; kt += 2) {
        stage_tile<BM, K>(A, A1, m0, (kt + 1) * 64, t);
        stage_tile<BN, K>(B, B1, n0, (kt + 1) * 64, t);
        compute(A0, B0);
        __syncthreads();
        if (kt + 2 < NK) {
            stage_tile<BM, K>(A, A0, m0, (kt + 2) * 64, t);
            stage_tile<BN, K>(B, B0, n0, (kt + 2) * 64, t);
        }
        compute(A1, B1);
        __syncthreads();
    }

#pragma unroll
    for (int fi = 0; fi < FM; fi++) {
#pragma unroll
        for (int fj = 0; fj < FN; fj++) {
#pragma unroll
            for (int r = 0; r < 4; r++) {
                const int row = m0 + wm0 + fi * 16 + g * 4 + r;
                const int col = n0 + wn0 + fj * 16 + l15;
                const float v = acc[fi][fj][r];
                if (EP == EP_R) {
                    ((unsigned short*)out0)[(size_t)row * N + col] =
                        f2bf(v - auxf[(size_t)row * N + col]);
                } else if (EP == EP_OUT) {
                    ((float*)out0)[(size_t)row * N + col] = v;
                } else { // EP_UUP
                    float* up = (float*)out0;
                    const size_t idx = (size_t)row * CAUSES_DIM + col;
                    const float uv = softthr(up[idx] - LR * v, LR * GAMMA * 0.1f);
                    up[idx] = uv;
                    ((unsigned short*)out1)[idx] = f2bf(uv);
                }
            }
        }
    }
}

// ---------------------------------------------------------------------------
// XUPC: x-update GEMM (R@W^T) + fused causes mini-GEMM (u@V) + fused pool/gin
// BM=BN=128, 64 KB LDS. czdc (cz|dc bf16 pairs) parked in dead B1 region.
// ---------------------------------------------------------------------------
template<bool POOLF>
__global__ __launch_bounds__(256)
void xupc_kernel(const unsigned short* __restrict__ Rbf,
                 const unsigned short* __restrict__ Wbf,
                 const unsigned short* __restrict__ ubf,
                 const unsigned short* __restrict__ VTbf,
                 unsigned short* __restrict__ xbf,
                 unsigned short* __restrict__ gbf)
{
    constexpr int BM = 128, BN = 128, K = IN_DIM, NK = K / 64;
    constexpr int NX = OUT_DIM / BN, NWG = (NB / BM) * NX;   // 32*32 = 1024
    constexpr int TILE = (BM + BN) * 64;                     // 16384 shorts
    __shared__ unsigned short lds[2 * TILE];                 // 64 KB
    unsigned short* A0 = lds;
    unsigned short* B0 = lds + BM * 64;
    unsigned short* A1 = lds + TILE;
    unsigned short* B1 = lds + TILE + BM * 64;
    unsigned* czdc = (unsigned*)(lds + 2 * TILE - 8192);     // 16 KB, = B1 tail
    unsigned short* xs = lds;                                // pool tile, 16640 shorts

    const int t    = threadIdx.x;
    const int lane = t & 63, wid = t >> 6;
    const int l15  = lane & 15, l7 = lane & 7, g = lane >> 4;
    const int work = ((blockIdx.x & 7) * (NWG / 8)) + (blockIdx.x >> 3);
    const int bn = work % NX, bm = work / NX;
    const int m0 = bm * BM, n0 = bn * BN;
    const int wm0 = (wid >> 1) * 64, wn0 = (wid & 1) * 64;

    f32x4 acc[4][4];
#pragma unroll
    for (int fi = 0; fi < 4; fi++)
#pragma unroll
        for (int fj = 0; fj < 4; fj++) acc[fi][fj] = (f32x4){0.f, 0.f, 0.f, 0.f};

    auto compute = [&](const unsigned short* As, const unsigned short* Bs) {
#pragma unroll
        for (int ks = 0; ks < 2; ks++) {
            const int so = (((ks * 4) + g) ^ l7) * 8;
            short8 af[4], bfv[4];
#pragma unroll
            for (int fi = 0; fi < 4; fi++)
                af[fi] = *(const short8*)&As[(wm0 + fi * 16 + l15) * 64 + so];
#pragma unroll
            for (int fj = 0; fj < 4; fj++)
                bfv[fj] = *(const short8*)&Bs[(wn0 + fj * 16 + l15) * 64 + so];
#pragma unroll
            for (int fi = 0; fi < 4; fi++)
#pragma unroll
                for (int fj = 0; fj < 4; fj++)
                    acc[fi][fj] = __builtin_amdgcn_mfma_f32_16x16x32_bf16(
                        af[fi], bfv[fj], acc[fi][fj], 0, 0, 0);
        }
    };

    // ---- main GEMM: acc = R[m0:,:] @ W^T[n0:,:] over K=512 ----
    stage_tile<BM, K>(Rbf, A0, m0, 0, t);
    stage_tile<BN, K>(Wbf, B0, n0, 0, t);
    __syncthreads();
#pragma unroll 1
    for (int kt = 0; kt < NK; kt += 2) {
        stage_tile<BM, K>(Rbf, A1, m0, (kt + 1) * 64, t);
        stage_tile<BN, K>(Wbf, B1, n0, (kt + 1) * 64, t);
        compute(A0, B0);
        __syncthreads();
        if (kt + 2 < NK) {
            stage_tile<BM, K>(Rbf, A0, m0, (kt + 2) * 64, t);
            stage_tile<BN, K>(Wbf, B0, n0, (kt + 2) * 64, t);
        }
        compute(A1, B1);
        __syncthreads();
    }

    // ---- causes mini-GEMM: z[128x32] = ubf[m0:,:256] @ VT[bn*32:,:256]^T ----
    f32x4 zacc[4];
#pragma unroll
    for (int fi = 0; fi < 4; fi++) zacc[fi] = (f32x4){0.f, 0.f, 0.f, 0.f};
    const int vrow0 = bn * 32;
    auto zcomp = [&](const unsigned short* As, const unsigned short* Bs) {
#pragma unroll
        for (int ks = 0; ks < 2; ks++) {
            const int so = (((ks * 4) + g) ^ l7) * 8;
            short8 bfv = *(const short8*)&Bs[((wid & 1) * 16 + l15) * 64 + so];
#pragma unroll
            for (int fi = 0; fi < 4; fi++) {
                short8 af = *(const short8*)&As[((wid >> 1) * 64 + fi * 16 + l15) * 64 + so];
                zacc[fi] = __builtin_amdgcn_mfma_f32_16x16x32_bf16(af, bfv, zacc[fi], 0, 0, 0);
            }
        }
    };
    stage_tile<128, CAUSES_DIM>(ubf, A0, m0, 0, t);
    stage_tile<32, CAUSES_DIM>(VTbf, B0, vrow0, 0, t);
    __syncthreads();
    stage_tile<128, CAUSES_DIM>(ubf, A1, m0, 64, t);
    stage_tile<32, CAUSES_DIM>(VTbf, B1, vrow0, 64, t);
    zcomp(A0, B0);
    __syncthreads();
    stage_tile<128, CAUSES_DIM>(ubf, A0, m0, 128, t);
    stage_tile<32, CAUSES_DIM>(VTbf, B0, vrow0, 128, t);
    zcomp(A1, B1);
    __syncthreads();
    stage_tile<128, CAUSES_DIM>(ubf, A1, m0, 192, t);
    stage_tile<32, CAUSES_DIM>(VTbf, B1, vrow0, 192, t);
    zcomp(A0, B0);
    __syncthreads();
    zcomp(A1, B1);
    __syncthreads();

    // z epilogue -> czdc LDS (cz low 16, dc high 16), bf16-rounded as before
#pragma unroll
    for (int fi = 0; fi < 4; fi++) {
#pragma unroll
        for (int r = 0; r < 4; r++) {
            const int zrow = (wid >> 1) * 64 + fi * 16 + g * 4 + r;
            const int zcol = (wid & 1) * 16 + l15;
            const float e = expf(-zacc[fi][r]);
            czdc[zrow * 32 + zcol] =
                (unsigned)f2bf(0.5f + 0.5f * e) | ((unsigned)f2bf(-0.5f * e) << 16);
        }
    }
    __syncthreads();

    // ---- x-update epilogue (reads cz from LDS, writes xbf + xs) ----
#pragma unroll
    for (int fi = 0; fi < 4; fi++) {
#pragma unroll
        for (int fj = 0; fj < 4; fj++) {
#pragma unroll
            for (int r = 0; r < 4; r++) {
                const int rloc = wm0 + fi * 16 + g * 4 + r;
                const int cloc = wn0 + fj * 16 + l15;
                const int pl = (cloc & 63) >> 1;
                const float cz = bf2f((unsigned short)(czdc[rloc * 32 + pl] & 0xffffu));
                const size_t idx = (size_t)(m0 + rloc) * OUT_DIM + n0 + cloc;
                const float xv = softthr(bf2f(xbf[idx]) - 2.0f * LR * acc[fi][fj][r],
                                         LR * GAMMA * cz);
                const unsigned short xq = f2bf(xv);
                xbf[idx] = xq;
                if (POOLF) xs[rloc * 130 + cloc] = xq;
            }
        }
    }

    // ---- fused maxpool2x2 + gin ----
    if (POOLF) {
        __syncthreads();
        const int p = t & 31;                 // local pooled col
        const int rbase = (t >> 5) * 16;      // 8 groups x 16 rows
#pragma unroll
        for (int i = 0; i < 16; i++) {
            const int prow = rbase + i;
            const unsigned short* xr = &xs[prow * 130 + 2 * p];
            const float mx = fmaxf(fmaxf(bf2f(xr[0]), bf2f(xr[1])),
                                   fmaxf(bf2f(xr[64]), bf2f(xr[65])));
            const float dcv = bf2f((unsigned short)(czdc[prow * 32 + p] >> 16));
            gbf[(size_t)(m0 + prow) * POOLED_DIM + bn * 32 + p] = f2bf(dcv * mx * GAMMA);
        }
    }
}

// ---------------------------------------------------------------------------
// H: horizontal fusion of UUP_t (256 blocks) and R_{t+1} (256 blocks)
// ---------------------------------------------------------------------------
__global__ __launch_bounds__(256)
void h_uup_r_kernel(const unsigned short* __restrict__ gbf,
                    const unsigned short* __restrict__ Vbf,
                    float* __restrict__ u, unsigned short* __restrict__ ubf,
                    const unsigned short* __restrict__ xbf,
                    const unsigned short* __restrict__ WTbf,
                    const float* __restrict__ inputs,
                    unsigned short* __restrict__ Rbf)
{
    __shared__ unsigned short lds[24576];   // 48 KB (R-part size)
    if (blockIdx.x < 256) {
        gemm_core<128, 64, IN_DIM, OUT_DIM, EP_R>(
            lds, blockIdx.x, xbf, WTbf, inputs, Rbf, nullptr);
    } else {
        gemm_core<64, 64, CAUSES_DIM, POOLED_DIM, EP_UUP>(
            lds, blockIdx.x - 256, gbf, Vbf, nullptr, u, ubf);
    }
}

__global__ __launch_bounds__(256)
void out_kernel(const unsigned short* __restrict__ xbf,
                const unsigned short* __restrict__ WTbf,
                float* __restrict__ out)
{
    __shared__ unsigned short lds[24576];
    gemm_core<128, 64, IN_DIM, OUT_DIM, EP_OUT>(
        lds, blockIdx.x, xbf, WTbf, nullptr, out, nullptr);
}

// ---------------------------------------------------------------------------
// setup kernels
// ---------------------------------------------------------------------------
__global__ void cast_bf16_k(const float* __restrict__ in, unsigned short* __restrict__ out,
                            int n4, int neg)
{
    const int i = blockIdx.x * 256 + threadIdx.x;
    if (i >= n4) return;
    float4 v = ((const float4*)in)[i];
    if (neg) { v.x = -v.x; v.y = -v.y; v.z = -v.z; v.w = -v.w; }
    union { unsigned short s[4]; unsigned long long u; } p;
    p.s[0] = f2bf(v.x); p.s[1] = f2bf(v.y); p.s[2] = f2bf(v.z); p.s[3] = f2bf(v.w);
    ((unsigned long long*)out)[i] = p.u;
}

__global__ __launch_bounds__(256)
void transpose_cast_k(const float* __restrict__ in, unsigned short* __restrict__ out,
                      int R, int C)
{
    __shared__ float tile[32][33];
    const int bx = blockIdx.x * 32, by = blockIdx.y * 32;
    const int tx = threadIdx.x % 32, ty = threadIdx.x / 32;
#pragma unroll
    for (int i = 0; i < 32; i += 8)
        tile[ty + i][tx] = in[(size_t)(by + ty + i) * C + bx + tx];
    __syncthreads();
#pragma unroll
    for (int i = 0; i < 32; i += 8)
        out[(size_t)(bx + ty + i) * R + by + tx] = f2bf(tile[tx][ty + i]);
}

__global__ void fill_zero_u16(unsigned short* __restrict__ p, size_t n8) {
    for (size_t i = (size_t)blockIdx.x * 256 + threadIdx.x; i < n8;
         i += (size_t)gridDim.x * 256)
        ((ulonglong2*)p)[i] = (ulonglong2){0ull, 0ull};
}

__global__ void fill_u_k(float* __restrict__ u, unsigned short* __restrict__ ubf, int n) {
    const int i = blockIdx.x * 256 + threadIdx.x;
    if (i >= n) return;
    u[i] = 0.1f;
    ubf[i] = f2bf(0.1f);
}

extern "C" void kernel_launch(void* const* d_in, const int* in_sizes, int n_in,
                              void* d_out, int out_size, void* d_ws, size_t ws_size,
                              hipStream_t stream)
{
    const float* inputs = (const float*)d_in[0];   // [4096, 512]
    const float* W      = (const float*)d_in[1];   // [4096, 512]
    const float* V      = (const float*)d_in[2];   // [256, 1024]
    float* out = (float*)d_out;                    // [4096, 512]

    // workspace (~59 MB)
    char* w = (char*)d_ws;
    unsigned short* xbf  = (unsigned short*)w; w += (size_t)NB * OUT_DIM * 2;
    unsigned short* Rbf  = (unsigned short*)w; w += (size_t)NB * IN_DIM * 2;
    unsigned short* gbf  = (unsigned short*)w; w += (size_t)NB * POOLED_DIM * 2;
    float*          u    = (float*)w;          w += (size_t)NB * CAUSES_DIM * 4;
    unsigned short* ubf  = (unsigned short*)w; w += (size_t)NB * CAUSES_DIM * 2;
    unsigned short* Wbf  = (unsigned short*)w; w += (size_t)OUT_DIM * IN_DIM * 2;
    unsigned short* WTbf = (unsigned short*)w; w += (size_t)OUT_DIM * IN_DIM * 2;
    unsigned short* Vbf  = (unsigned short*)w; w += (size_t)CAUSES_DIM * POOLED_DIM * 2;
    unsigned short* VTbf = (unsigned short*)w;

    // ---- setup (7 launches) ----
    cast_bf16_k<<<OUT_DIM * IN_DIM / 4 / 256, 256, 0, stream>>>(W, Wbf, OUT_DIM * IN_DIM / 4, 0);
    cast_bf16_k<<<CAUSES_DIM * POOLED_DIM / 4 / 256, 256, 0, stream>>>(V, Vbf, CAUSES_DIM * POOLED_DIM / 4, 0);
    transpose_cast_k<<<dim3(IN_DIM / 32, OUT_DIM / 32), 256, 0, stream>>>(W, WTbf, OUT_DIM, IN_DIM);
    transpose_cast_k<<<dim3(POOLED_DIM / 32, CAUSES_DIM / 32), 256, 0, stream>>>(V, VTbf, CAUSES_DIM, POOLED_DIM);
    fill_zero_u16<<<2048, 256, 0, stream>>>(xbf, (size_t)NB * OUT_DIM / 8);
    fill_u_k<<<NB * CAUSES_DIM / 256, 256, 0, stream>>>(u, ubf, NB * CAUSES_DIM);
    cast_bf16_k<<<NB * IN_DIM / 4 / 256, 256, 0, stream>>>(inputs, Rbf, NB * IN_DIM / 4, 1); // R0=-inputs

    // ---- 10-step scan: 2 launches per step ----
    for (int t = 0; t < 8; t++) {
        xupc_kernel<true><<<1024, 256, 0, stream>>>(Rbf, Wbf, ubf, VTbf, xbf, gbf);
        h_uup_r_kernel<<<512, 256, 0, stream>>>(gbf, Vbf, u, ubf, xbf, WTbf, inputs, Rbf);
    }
    xupc_kernel<false><<<1024, 256, 0, stream>>>(Rbf, Wbf, ubf, VTbf, xbf, gbf); // t=8
    out_kernel<<<256, 256, 0, stream>>>(xbf, WTbf, out);                          // rec = x9@W
}